// Round 10
// baseline (1768.539 us; speedup 1.0000x reference)
//
#include <hip/hip_runtime.h>
#include <hip/hip_bf16.h>

#define SQ 1024
#define DM 768
#define NH 12
#define NL 6
#define NV 32000
#define KDH 64
#define FFD 3072

using bf16 = __hip_bfloat16;
typedef __attribute__((ext_vector_type(4))) float f32x4;
typedef __attribute__((ext_vector_type(8))) short bf16x8;

// ---------------- diagnostic fill (fp32 out) ----------------
__global__ void fill_kernel(float* __restrict__ out, long n, float val) {
  const long stride = (long)gridDim.x * blockDim.x;
  for (long i = (long)blockIdx.x * blockDim.x + threadIdx.x; i < n; i += stride)
    out[i] = val;
}

// async global->LDS, 16 bytes per lane
__device__ __forceinline__ void gload16(const void* g, void* l) {
  __builtin_amdgcn_global_load_lds(
      (const __attribute__((address_space(1))) unsigned int*)g,
      (__attribute__((address_space(3))) unsigned int*)l, 16, 0, 0);
}

// ---------------- 128x128 MFMA GEMM, counted-vmcnt double-buffer ----------------
// CSKIP: skip tiles with n0 > m0 (causal upper triangle; P overwritten by softmax).
// CTRUNC: truncate K to m0+128 (causal PV: P[s,t]=0 for t>s on non-pad rows;
//         pad rows overridden analytically in ln_kernel via vmean).
template<bool OUT_BF16, bool RELU, bool CSKIP = false, bool CTRUNC = false>
__global__ __launch_bounds__(256) void gemm_bt(
    int M, int N, int K,
    const bf16* __restrict__ Ap, long sAz, int lda,
    const bf16* __restrict__ Bp, long sBz, int ldbt,
    const float* __restrict__ biasp, int sBiasZ,
    void* __restrict__ Cp, long sCz, long sCb, long sCs, long sCn)
{
  __shared__ __align__(16) char lds[32768];   // buf0: A 8K | B 8K ; buf1: +16384
  char* const As = lds;
  char* const Bs = lds + 8192;

  const int tid = threadIdx.x;
  // bijective XCD-aware block swizzle
  const int gx = gridDim.x, gy = gridDim.y;
  const int nwg = gx * gy * (int)gridDim.z;
  int flat = ((int)blockIdx.z * gy + (int)blockIdx.y) * gx + (int)blockIdx.x;
  {
    const int q = nwg >> 3, r = nwg & 7;
    const int xcd = flat & 7, loc = flat >> 3;
    flat = (xcd < r ? xcd * (q + 1) : r * (q + 1) + (xcd - r) * q) + loc;
  }
  const int bx  = flat % gx;
  const int byz = flat / gx;
  const int m0 = bx * 128;
  const int n0 = (byz % gy) * 128;
  const int z  = byz / gy;

  if (CSKIP && n0 > m0) return;              // fully-masked causal tile
  const int KK = CTRUNC ? min(K, m0 + 128) : K;

  const int lane = tid & 63;
  const int wid  = tid >> 6;
  const int wm = (wid >> 1) * 64;
  const int wn = (wid & 1) * 64;

  const int srow  = tid >> 2;
  const int sslot = tid & 3;
  const int xorb  = (sslot ^ (srow & 3)) << 4;

  const char* gA0 = (const char*)(Ap + (long)z * sAz + (long)(m0 + srow) * lda) + xorb;
  const char* gA1 = (const char*)(Ap + (long)z * sAz + (long)(m0 + srow + 64) * lda) + xorb;
  const char* gB0 = (const char*)(Bp + (long)z * sBz + (long)(n0 + srow) * ldbt) + xorb;
  const char* gB1 = (const char*)(Bp + (long)z * sBz + (long)(n0 + srow + 64) * ldbt) + xorb;

  auto stage = [&](int dstOfs) {
    gload16(gA0, As + dstOfs + tid * 16);
    gload16(gA1, As + dstOfs + (tid + 256) * 16);
    gload16(gB0, Bs + dstOfs + tid * 16);
    gload16(gB1, Bs + dstOfs + (tid + 256) * 16);
    gA0 += 64; gA1 += 64; gB0 += 64; gB1 += 64;
  };

  const int fr = lane & 15;
  const int kq = lane >> 4;
  const char* fA[4];
  const char* fB[4];
#pragma unroll
  for (int m = 0; m < 4; ++m) {
    const int R = wm + m * 16 + fr;
    fA[m] = As + R * 64 + ((kq ^ (R & 3)) << 4);
  }
#pragma unroll
  for (int n = 0; n < 4; ++n) {
    const int R = wn + n * 16 + fr;
    fB[n] = Bs + R * 64 + ((kq ^ (R & 3)) << 4);
  }

  f32x4 acc[4][4] = {};

  stage(0);                        // prologue: tile 0 -> buf0
  int cur = 0;
  for (int kt = 0; kt < KK; kt += 32) {
    if (kt + 32 < KK) {
      stage((cur ^ 1) * 16384);    // tile t+1 -> other buf (8 in flight)
      asm volatile("s_waitcnt vmcnt(4)" ::: "memory");   // tile t landed
    } else {
      asm volatile("s_waitcnt vmcnt(0)" ::: "memory");
    }
    __builtin_amdgcn_s_barrier();
    const int co = cur * 16384;
    bf16x8 af[4], bfr[4];
#pragma unroll
    for (int m = 0; m < 4; ++m) af[m] = *(const bf16x8*)(fA[m] + co);
#pragma unroll
    for (int n = 0; n < 4; ++n) bfr[n] = *(const bf16x8*)(fB[n] + co);
#pragma unroll
    for (int m = 0; m < 4; ++m)
#pragma unroll
      for (int n = 0; n < 4; ++n)
        acc[m][n] = __builtin_amdgcn_mfma_f32_16x16x32_bf16(af[m], bfr[n], acc[m][n], 0, 0, 0);
    __builtin_amdgcn_s_barrier();
    cur ^= 1;
  }

  const int rg = (lane >> 4) * 4;
  const int cl = lane & 15;
#pragma unroll
  for (int n = 0; n < 4; ++n) {
    const int gcol = n0 + wn + n * 16 + cl;
    float bias = 0.f;
    if (biasp) bias = biasp[(long)z * sBiasZ + gcol];
    if (OUT_BF16 && sCs == 1) {
#pragma unroll
      for (int m = 0; m < 4; ++m) {
        const int grow = m0 + wm + m * 16 + rg;
        const long ci = (long)z * sCz + (long)(grow >> 10) * sCb
                      + (long)(grow & 1023) + (long)gcol * sCn;
        ushort4 pk;
        float v0 = acc[m][n][0] + bias, v1 = acc[m][n][1] + bias;
        float v2 = acc[m][n][2] + bias, v3 = acc[m][n][3] + bias;
        if (RELU) { v0 = fmaxf(v0, 0.f); v1 = fmaxf(v1, 0.f);
                    v2 = fmaxf(v2, 0.f); v3 = fmaxf(v3, 0.f); }
        pk.x = __builtin_bit_cast(ushort, __float2bfloat16(v0));
        pk.y = __builtin_bit_cast(ushort, __float2bfloat16(v1));
        pk.z = __builtin_bit_cast(ushort, __float2bfloat16(v2));
        pk.w = __builtin_bit_cast(ushort, __float2bfloat16(v3));
        *(ushort4*)((bf16*)Cp + ci) = pk;
      }
    } else {
#pragma unroll
      for (int m = 0; m < 4; ++m) {
#pragma unroll
        for (int rr = 0; rr < 4; ++rr) {
          const int grow = m0 + wm + m * 16 + rg + rr;
          float v = acc[m][n][rr] + bias;
          if (RELU) v = fmaxf(v, 0.f);
          const long ci = (long)z * sCz + (long)(grow >> 10) * sCb
                        + (long)(grow & 1023) * sCs + (long)gcol * sCn;
          if (OUT_BF16) ((bf16*)Cp)[ci] = __float2bfloat16(v);
          else          ((float*)Cp)[ci] = v;
        }
      }
    }
  }
}

// ---------------- fp32 [Kd,Nd] -> bf16 [Nd,Kd] transpose ----------------
__global__ __launch_bounds__(256) void transpose_kernel(
    const float* __restrict__ in, long sInZ, int ldin,
    bf16* __restrict__ out, long sOutZ, int ldout)
{
  __shared__ float t[64][65];
  const int tid = threadIdx.x;
  const int n0 = blockIdx.x * 64, k0 = blockIdx.y * 64;
  const float* ip = in + (long)blockIdx.z * sInZ;
  bf16* op = out + (long)blockIdx.z * sOutZ;
  const int cx = (tid & 15) * 4, ry = tid >> 4;
#pragma unroll
  for (int p = 0; p < 4; ++p) {
    const int k = ry + p * 16;
    const float4 v = *(const float4*)(ip + (long)(k0 + k) * ldin + n0 + cx);
    t[k][cx] = v.x; t[k][cx + 1] = v.y; t[k][cx + 2] = v.z; t[k][cx + 3] = v.w;
  }
  __syncthreads();
#pragma unroll
  for (int p = 0; p < 4; ++p) {
    const int n = ry + p * 16;
    ushort4 o;
    o.x = __builtin_bit_cast(ushort, __float2bfloat16(t[cx + 0][n]));
    o.y = __builtin_bit_cast(ushort, __float2bfloat16(t[cx + 1][n]));
    o.z = __builtin_bit_cast(ushort, __float2bfloat16(t[cx + 2][n]));
    o.w = __builtin_bit_cast(ushort, __float2bfloat16(t[cx + 3][n]));
    *(ushort4*)(op + (long)(n0 + n) * ldout + k0 + cx) = o;
  }
}

// ---------------- stacked Q/K bias ----------------
__global__ void biasqk_kernel(const float* __restrict__ bq, const float* __restrict__ bk,
                              float* __restrict__ out) {
  const int i = blockIdx.x * 256 + threadIdx.x;
  if (i < NH * 128) {
    const int h = i >> 7, n = i & 127;
    out[i] = (n < 64) ? bq[h * 64 + n] : bk[h * 64 + n - 64];
  }
}

// ---------------- xmean pipeline (analytic pad-row attention) ----------------
// xpart[(b*16+g)][d] = sum of 64 rows of x
__global__ __launch_bounds__(256) void xpart_kernel(
    const float* __restrict__ x, float* __restrict__ xpart) {
  const int b = blockIdx.x, g = blockIdx.y;
  const int tid = threadIdx.x;
  const float* xp = x + (long)b * SQ * DM + (long)g * 64 * DM;
  float a0 = 0.f, a1 = 0.f, a2 = 0.f;
  for (int s = 0; s < 64; ++s) {
    a0 += xp[(long)s * DM + tid];
    a1 += xp[(long)s * DM + tid + 256];
    a2 += xp[(long)s * DM + tid + 512];
  }
  float* op = xpart + (long)(b * 16 + g) * DM;
  op[tid] = a0; op[tid + 256] = a1; op[tid + 512] = a2;
}

// xmean[b][d] = (1/SQ) * sum_g xpart
__global__ void xmeanf_kernel(const float* __restrict__ xpart, float* __restrict__ xmean) {
  const int b = blockIdx.x;
  const int d = threadIdx.x;   // 768 threads
  float a = 0.f;
#pragma unroll
  for (int g = 0; g < 16; ++g) a += xpart[(long)(b * 16 + g) * DM + d];
  xmean[b * DM + d] = a * (1.0f / (float)SQ);
}

// vmean[b][e] = (1/H) * sum_h ( dot(xmean[b,:], wvT[h,e,:]) + bv[h,e] )
__global__ __launch_bounds__(256) void vmeanw_kernel(
    const float* __restrict__ xmean, const bf16* __restrict__ wvT,
    const float* __restrict__ bv, float* __restrict__ vmean) {
  const int tid = threadIdx.x;
  const int w = blockIdx.x * 4 + (tid >> 6);   // 0..1535
  const int b = w / DM;
  const int e = w % DM;
  const int lane = tid & 63;
  float xm[12];
#pragma unroll
  for (int j = 0; j < 12; ++j) xm[j] = xmean[b * DM + lane + j * 64];
  float acc = 0.f;
  for (int h = 0; h < NH; ++h) {
    const bf16* wr = wvT + ((long)h * DM + e) * DM;
#pragma unroll
    for (int j = 0; j < 12; ++j)
      acc += xm[j] * __bfloat162float(wr[lane + j * 64]);
  }
#pragma unroll
  for (int o = 32; o >= 1; o >>= 1) acc += __shfl_xor(acc, o);
  if (lane == 0) {
    float bs = 0.f;
#pragma unroll
    for (int h = 0; h < NH; ++h) bs += bv[h * DM + e];
    vmean[b * DM + e] = (acc + bs) * (1.0f / (float)NH);
  }
}

// ---------------- embedding + PE -> x fp32 + xb bf16 ----------------
__global__ __launch_bounds__(256) void embed_kernel(
    const int* __restrict__ tok, const float* __restrict__ emb,
    float* __restrict__ x, bf16* __restrict__ xb)
{
  const int gid = blockIdx.x * 256 + threadIdx.x;
  const int row = gid / (DM / 4);
  const int dc  = (gid % (DM / 4)) * 4;
  const int t = tok[row];
  const int s = row & (SQ - 1);
#pragma unroll
  for (int j = 0; j < 4; ++j) {
    const int d = dc + j;
    const float e = emb[(long)t * DM + d];
    const float div = expf(-(float)(d & ~1) * (9.210340371976184f / (float)DM));
    const float ang = (float)s * div;
    const float pe = (d & 1) ? cosf(ang) : sinf(ang);
    const float v = e + pe;
    x[(long)row * DM + d] = v;
    xb[(long)row * DM + d] = __float2bfloat16(v);
  }
}

// ---------------- masked softmax ----------------
__global__ __launch_bounds__(256) void softmax_kernel(
    bf16* __restrict__ P, const int* __restrict__ tok)
{
  const int row = blockIdx.x;
  const int s = row & (SQ - 1);
  const int z = row >> 10;
  const int b = z / NH;
  bf16* sp = P + (long)row * SQ;
  const int* tb = tok + b * SQ;
  const int tid = threadIdx.x;
  const int t0 = tid * 4;

  if (tb[s] == 0) {
    const bf16 u = __float2bfloat16(1.0f / (float)SQ);
    sp[t0] = u; sp[t0 + 1] = u; sp[t0 + 2] = u; sp[t0 + 3] = u;
    return;
  }
  uint2 raw = *(const uint2*)(sp + t0);
  int4 tv = *(const int4*)(tb + t0);
  const bf16* rh = (const bf16*)&raw;
  const int tvv[4] = {tv.x, tv.y, tv.z, tv.w};
  float val[4];
  float vmax = -1e30f;
#pragma unroll
  for (int j = 0; j < 4; ++j) {
    const int t = t0 + j;
    const bool valid = (t <= s) && (tvv[j] != 0);
    val[j] = valid ? __bfloat162float(rh[j]) * 0.125f : -1e30f;
    vmax = fmaxf(vmax, val[j]);
  }
  __shared__ float red[4];
  const int lane = tid & 63, wid = tid >> 6;
  float w = vmax;
#pragma unroll
  for (int o = 32; o >= 1; o >>= 1) w = fmaxf(w, __shfl_xor(w, o));
  if (lane == 0) red[wid] = w;
  __syncthreads();
  const float Mx = fmaxf(fmaxf(red[0], red[1]), fmaxf(red[2], red[3]));
  __syncthreads();
  float e[4]; float lsum = 0.f;
#pragma unroll
  for (int j = 0; j < 4; ++j) {
    e[j] = (val[j] > -1e29f) ? expf(val[j] - Mx) : 0.f;
    lsum += e[j];
  }
  w = lsum;
#pragma unroll
  for (int o = 32; o >= 1; o >>= 1) w += __shfl_xor(w, o);
  if (lane == 0) red[wid] = w;
  __syncthreads();
  const float inv = 1.0f / (red[0] + red[1] + red[2] + red[3]);
#pragma unroll
  for (int j = 0; j < 4; ++j) sp[t0 + j] = __float2bfloat16(e[j] * inv);
}

// ---------------- residual (+head-mean / pad-override) + LayerNorm ----------------
template<int MODE>
__global__ __launch_bounds__(256) void ln_kernel(
    float* __restrict__ x, bf16* __restrict__ xb,
    const float* __restrict__ tmp, const bf16* __restrict__ heads,
    const float* __restrict__ g, const float* __restrict__ be,
    const int* __restrict__ tok, const float* __restrict__ vmean)
{
  const int r = blockIdx.x;
  const int b = r >> 10;
  const int tid = threadIdx.x;
  const bool pad = (MODE == 1) && (tok[r] == 0);
  float vals[3];
  float sum = 0.f, sq = 0.f;
#pragma unroll
  for (int i = 0; i < 3; ++i) {
    const int d = tid + i * 256;
    const float a = x[(long)r * DM + d];
    float t;
    if (MODE == 0) {
      t = tmp[(long)r * DM + d];
    } else if (pad) {
      t = vmean[b * DM + d];       // analytic uniform-attention output
    } else {
      const int s = r & (SQ - 1);
      float hs = 0.f;
#pragma unroll
      for (int h = 0; h < NH; ++h)
        hs += __bfloat162float(heads[((long)(b * NH + h) * SQ + s) * DM + d]);
      t = hs * (1.0f / (float)NH);
    }
    const float vv = a + t;
    vals[i] = vv;
    sum += vv; sq += vv * vv;
  }
  __shared__ float rs[4], rq[4];
  const int lane = tid & 63, wid = tid >> 6;
  float s1 = sum, s2 = sq;
#pragma unroll
  for (int o = 32; o >= 1; o >>= 1) { s1 += __shfl_xor(s1, o); s2 += __shfl_xor(s2, o); }
  if (lane == 0) { rs[wid] = s1; rq[wid] = s2; }
  __syncthreads();
  const float S1 = rs[0] + rs[1] + rs[2] + rs[3];
  const float S2 = rq[0] + rq[1] + rq[2] + rq[3];
  const float mean = S1 * (1.0f / (float)DM);
  const float var  = S2 * (1.0f / (float)DM) - mean * mean;
  const float rstd = rsqrtf(var + 1e-5f);
#pragma unroll
  for (int i = 0; i < 3; ++i) {
    const int d = tid + i * 256;
    const float o = (vals[i] - mean) * rstd * g[d] + be[d];
    x[(long)r * DM + d] = o;
    xb[(long)r * DM + d] = __float2bfloat16(o);
  }
}

extern "C" void kernel_launch(void* const* d_in, const int* in_sizes, int n_in,
                              void* d_out, int out_size, void* d_ws, size_t ws_size,
                              hipStream_t stream) {
  const int expect_sizes[18] = {
    2048, 24576000, 3538944, 4608, 3538944, 4608, 42467328, 55296,
    4608, 4608, 4608, 4608, 14155776, 18432, 14155776, 4608, 24576000, 32000
  };
  bool sizes_ok = (n_in == 18);
  if (sizes_ok)
    for (int i = 0; i < 18; ++i) sizes_ok = sizes_ok && (in_sizes[i] == expect_sizes[i]);
  if (!sizes_ok) {
    fill_kernel<<<2048, 256, 0, stream>>>((float*)d_out, (long)out_size, 1000.0f);
    return;
  }
  if (out_size != 65536000) {
    fill_kernel<<<2048, 256, 0, stream>>>((float*)d_out, (long)out_size, 3000.0f);
    return;
  }
  if (ws_size < 158189568ull) {   // r4 passed a 160432128 check -> ws >= that
    fill_kernel<<<2048, 256, 0, stream>>>((float*)d_out, (long)out_size, 2000.0f);
    return;
  }

  const int*   tok  = (const int*)d_in[0];
  const float* emb  = (const float*)d_in[1];
  const float* Wq   = (const float*)d_in[2];
  const float* bq   = (const float*)d_in[3];
  const float* Wk   = (const float*)d_in[4];
  const float* bk   = (const float*)d_in[5];
  const float* Wv   = (const float*)d_in[6];
  const float* bv   = (const float*)d_in[7];
  const float* g1   = (const float*)d_in[8];
  const float* be1  = (const float*)d_in[9];
  const float* g2   = (const float*)d_in[10];
  const float* be2  = (const float*)d_in[11];
  const float* W1   = (const float*)d_in[12];
  const float* b1   = (const float*)d_in[13];
  const float* W2   = (const float*)d_in[14];
  const float* b2   = (const float*)d_in[15];
  const float* Wout = (const float*)d_in[16];
  const float* bout = (const float*)d_in[17];

  char* ws = (char*)d_ws;
  float* x      = (float*)(ws + 0);
  bf16*  xb     = (bf16*) (ws + 6291456);
  bf16*  qk     = (bf16*) (ws + 9437184);
  float* tmp    = (float*)(ws + 9437184);
  bf16*  vT     = (bf16*) (ws + 15728640);
  bf16*  P      = (bf16*) (ws + 53477376);
  bf16*  ff     = (bf16*) (ws + 53477376);
  bf16*  woutT  = (bf16*) (ws + 53477376);
  bf16*  heads  = (bf16*) (ws + 103809024);
  bf16*  wqkT   = (bf16*) (ws + 141557760);
  bf16*  wvT    = (bf16*) (ws + 143917056);
  bf16*  w1T    = (bf16*) (ws + 141557760);
  bf16*  w2T    = (bf16*) (ws + 146276352);
  float* biasqk = (float*)(ws + 158072832);   // 6144 B
  float* xpart  = (float*)(ws + 158078976);   // 98304 B
  float* xmean  = (float*)(ws + 158177280);   // 6144 B
  float* vmean  = (float*)(ws + 158183424);   // 6144 B (end 158189568)

  embed_kernel<<<dim3((2 * SQ * DM / 4) / 256), 256, 0, stream>>>(tok, emb, x, xb);

  for (int l = 0; l < NL; ++l) {
    transpose_kernel<<<dim3(1, 12, NH), 256, 0, stream>>>(
        Wq + (long)l * NH * DM * KDH, (long)DM * KDH, KDH,
        wqkT, 128 * DM, DM);
    transpose_kernel<<<dim3(1, 12, NH), 256, 0, stream>>>(
        Wk + (long)l * NH * DM * KDH, (long)DM * KDH, KDH,
        wqkT + 64 * DM, 128 * DM, DM);
    transpose_kernel<<<dim3(12, 12, NH), 256, 0, stream>>>(
        Wv + (long)l * NH * DM * DM, (long)DM * DM, DM,
        wvT, (long)DM * DM, DM);
    biasqk_kernel<<<6, 256, 0, stream>>>(bq + l * NH * KDH, bk + l * NH * KDH, biasqk);

    // analytic pad-row attention: vmean[b,e] = mean_h(mean_t V_h)
    xpart_kernel<<<dim3(2, 16), 256, 0, stream>>>(x, xpart);
    xmeanf_kernel<<<dim3(2), 768, 0, stream>>>(xpart, xmean);
    vmeanw_kernel<<<dim3(384), 256, 0, stream>>>(xmean, wvT, bv + (long)l * NH * DM, vmean);

    // fused Q|K projection
    gemm_bt<true, false><<<dim3(16, 1, NH), 256, 0, stream>>>(
        2048, 128, DM, xb, 0, DM, wqkT, (long)128 * DM, DM,
        biasqk, 128,
        qk, (long)SQ * 128, (long)NH * SQ * 128, 128, 1);
    // V projection, written transposed vT[b,h,e,s]
    gemm_bt<true, false><<<dim3(16, 6, NH), 256, 0, stream>>>(
        2048, DM, DM, xb, 0, DM, wvT, (long)DM * DM, DM,
        bv + (long)l * NH * DM, DM,
        vT, (long)DM * SQ, (long)NH * DM * SQ, 1, SQ);
    // scores = Q @ K^T -> P  (causal tile skip; softmax overwrites every entry)
    gemm_bt<true, false, true, false><<<dim3(8, 8, 2 * NH), 256, 0, stream>>>(
        SQ, SQ, KDH, qk, (long)SQ * 128, 128, qk + 64, (long)SQ * 128, 128,
        (const float*)nullptr, 0,
        P, (long)SQ * SQ, 0, SQ, 1);
    softmax_kernel<<<dim3(2 * NH * SQ), 256, 0, stream>>>(P, tok);
    // heads = P @ V  (causal K-truncation; pad rows overridden in ln)
    gemm_bt<true, false, false, true><<<dim3(8, 6, 2 * NH), 256, 0, stream>>>(
        SQ, DM, SQ, P, (long)SQ * SQ, SQ, vT, (long)DM * SQ, SQ,
        (const float*)nullptr, 0,
        heads, (long)SQ * DM, 0, DM, 1);
    ln_kernel<1><<<dim3(2048), 256, 0, stream>>>(x, xb, nullptr, heads,
                                                 g1 + l * DM, be1 + l * DM, tok, vmean);
    transpose_kernel<<<dim3(48, 12, 1), 256, 0, stream>>>(
        W1 + (long)l * DM * FFD, 0, FFD, w1T, 0, DM);
    transpose_kernel<<<dim3(12, 48, 1), 256, 0, stream>>>(
        W2 + (long)l * FFD * DM, 0, DM, w2T, 0, FFD);
    gemm_bt<true, true><<<dim3(16, 24, 1), 256, 0, stream>>>(
        2048, FFD, DM, xb, 0, DM, w1T, 0, DM,
        b1 + (long)l * FFD, 0,
        ff, 0, (long)SQ * FFD, FFD, 1);
    gemm_bt<false, false><<<dim3(16, 6, 1), 256, 0, stream>>>(
        2048, DM, FFD, ff, 0, FFD, w2T, 0, FFD,
        b2 + (long)l * DM, 0,
        tmp, 0, (long)SQ * DM, DM, 1);
    ln_kernel<0><<<dim3(2048), 256, 0, stream>>>(x, xb, tmp, nullptr,
                                                 g2 + l * DM, be2 + l * DM, tok, nullptr);
  }
  transpose_kernel<<<dim3(500, 12, 1), 256, 0, stream>>>(Wout, 0, NV, woutT, 0, DM);
  gemm_bt<false, false><<<dim3(16, 250, 1), 256, 0, stream>>>(
      2048, NV, DM, xb, 0, DM, woutT, 0, DM,
      bout, 0,
      d_out, 0, (long)SQ * NV, NV, 1);
}

// Round 11
// 1716.754 us; speedup vs baseline: 1.0302x; 1.0302x over previous
//
#include <hip/hip_runtime.h>
#include <hip/hip_bf16.h>

#define SQ 1024
#define DM 768
#define NH 12
#define NL 6
#define NV 32000
#define KDH 64
#define FFD 3072

using bf16 = __hip_bfloat16;
typedef __attribute__((ext_vector_type(4))) float f32x4;
typedef __attribute__((ext_vector_type(8))) short bf16x8;

// ---------------- diagnostic fill (fp32 out) ----------------
__global__ void fill_kernel(float* __restrict__ out, long n, float val) {
  const long stride = (long)gridDim.x * blockDim.x;
  for (long i = (long)blockIdx.x * blockDim.x + threadIdx.x; i < n; i += stride)
    out[i] = val;
}

// async global->LDS, 16 bytes per lane
__device__ __forceinline__ void gload16(const void* g, void* l) {
  __builtin_amdgcn_global_load_lds(
      (const __attribute__((address_space(1))) unsigned int*)g,
      (__attribute__((address_space(3))) unsigned int*)l, 16, 0, 0);
}

// ---------------- 128x128 MFMA GEMM, 3-buffer 2-ahead counted-vmcnt ----------------
// Pipeline: prologue stages t0,t1; iter t stages t+2 -> buf[(t+2)%3], then
// vmcnt(8) retires ONLY tile t (t+1,t+2 stay in flight across the barrier).
// Tail: vmcnt(4) at nt-2, vmcnt(0) at nt-1. Wait ~= latency - 2*compute ~= 0.
// CSKIP: skip tiles with n0 > m0 (causal; P overwritten by softmax).
// CTRUNC: truncate K to m0+128 (causal PV; pad rows overridden via vmean).
template<bool OUT_BF16, bool RELU, bool CSKIP = false, bool CTRUNC = false>
__global__ __launch_bounds__(256) void gemm_bt(
    int M, int N, int K,
    const bf16* __restrict__ Ap, long sAz, int lda,
    const bf16* __restrict__ Bp, long sBz, int ldbt,
    const float* __restrict__ biasp, int sBiasZ,
    void* __restrict__ Cp, long sCz, long sCb, long sCs, long sCn)
{
  __shared__ __align__(16) char lds[49152];   // 3 bufs x (A 8K | B 8K)

  const int tid = threadIdx.x;
  // bijective XCD-aware block swizzle
  const int gx = gridDim.x, gy = gridDim.y;
  const int nwg = gx * gy * (int)gridDim.z;
  int flat = ((int)blockIdx.z * gy + (int)blockIdx.y) * gx + (int)blockIdx.x;
  {
    const int q = nwg >> 3, r = nwg & 7;
    const int xcd = flat & 7, loc = flat >> 3;
    flat = (xcd < r ? xcd * (q + 1) : r * (q + 1) + (xcd - r) * q) + loc;
  }
  const int bx  = flat % gx;
  const int byz = flat / gx;
  const int m0 = bx * 128;
  const int n0 = (byz % gy) * 128;
  const int z  = byz / gy;

  if (CSKIP && n0 > m0) return;              // fully-masked causal tile
  const int KK = CTRUNC ? min(K, m0 + 128) : K;

  const int lane = tid & 63;
  const int wid  = tid >> 6;
  const int wm = (wid >> 1) * 64;
  const int wn = (wid & 1) * 64;

  const int srow  = tid >> 2;
  const int sslot = tid & 3;
  const int xorb  = (sslot ^ (srow & 3)) << 4;

  const char* gA0 = (const char*)(Ap + (long)z * sAz + (long)(m0 + srow) * lda) + xorb;
  const char* gA1 = (const char*)(Ap + (long)z * sAz + (long)(m0 + srow + 64) * lda) + xorb;
  const char* gB0 = (const char*)(Bp + (long)z * sBz + (long)(n0 + srow) * ldbt) + xorb;
  const char* gB1 = (const char*)(Bp + (long)z * sBz + (long)(n0 + srow + 64) * ldbt) + xorb;

  auto stage = [&](int bo) {                 // one 128x32 A-tile + B-tile -> buf bo
    gload16(gA0, lds + bo + tid * 16);
    gload16(gA1, lds + bo + (tid + 256) * 16);
    gload16(gB0, lds + bo + 8192 + tid * 16);
    gload16(gB1, lds + bo + 8192 + (tid + 256) * 16);
    gA0 += 64; gA1 += 64; gB0 += 64; gB1 += 64;
  };

  // K-invariant fragment LDS offsets (buf0; add buf offset at use)
  const int fr = lane & 15;
  const int kq = lane >> 4;
  int fA[4], fB[4];
#pragma unroll
  for (int m = 0; m < 4; ++m) {
    const int R = wm + m * 16 + fr;
    fA[m] = R * 64 + ((kq ^ (R & 3)) << 4);
  }
#pragma unroll
  for (int n = 0; n < 4; ++n) {
    const int R = wn + n * 16 + fr;
    fB[n] = 8192 + R * 64 + ((kq ^ (R & 3)) << 4);
  }

  f32x4 acc[4][4] = {};

  const int nt = KK >> 5;                    // >= 4 at every call site
  stage(0);                                  // t0 -> buf0
  stage(16384);                              // t1 -> buf1
  int cur = 0;
  for (int t = 0; t < nt; ++t) {
    if (t + 2 < nt) {
      int nb = cur + 2; if (nb >= 3) nb -= 3;
      stage(nb * 16384);                     // t+2 in flight
      asm volatile("s_waitcnt vmcnt(8)" ::: "memory");   // tile t landed
    } else if (t + 1 < nt) {
      asm volatile("s_waitcnt vmcnt(4)" ::: "memory");
    } else {
      asm volatile("s_waitcnt vmcnt(0)" ::: "memory");
    }
    __builtin_amdgcn_s_barrier();            // tile t resident for ALL waves
    const int co = cur * 16384;
    bf16x8 af[4], bfr[4];
#pragma unroll
    for (int m = 0; m < 4; ++m) af[m] = *(const bf16x8*)(lds + co + fA[m]);
#pragma unroll
    for (int n = 0; n < 4; ++n) bfr[n] = *(const bf16x8*)(lds + co + fB[n]);
#pragma unroll
    for (int m = 0; m < 4; ++m)
#pragma unroll
      for (int n = 0; n < 4; ++n)
        acc[m][n] = __builtin_amdgcn_mfma_f32_16x16x32_bf16(af[m], bfr[n], acc[m][n], 0, 0, 0);
    __builtin_amdgcn_s_barrier();            // all waves done reading buf cur
    cur = (cur == 2) ? 0 : cur + 1;
  }

  // epilogue: C/D layout col=lane&15, row=(lane>>4)*4+reg
  const int rg = (lane >> 4) * 4;
  const int cl = lane & 15;
#pragma unroll
  for (int n = 0; n < 4; ++n) {
    const int gcol = n0 + wn + n * 16 + cl;
    float bias = 0.f;
    if (biasp) bias = biasp[(long)z * sBiasZ + gcol];
    if (OUT_BF16 && sCs == 1) {
#pragma unroll
      for (int m = 0; m < 4; ++m) {
        const int grow = m0 + wm + m * 16 + rg;
        const long ci = (long)z * sCz + (long)(grow >> 10) * sCb
                      + (long)(grow & 1023) + (long)gcol * sCn;
        ushort4 pk;
        float v0 = acc[m][n][0] + bias, v1 = acc[m][n][1] + bias;
        float v2 = acc[m][n][2] + bias, v3 = acc[m][n][3] + bias;
        if (RELU) { v0 = fmaxf(v0, 0.f); v1 = fmaxf(v1, 0.f);
                    v2 = fmaxf(v2, 0.f); v3 = fmaxf(v3, 0.f); }
        pk.x = __builtin_bit_cast(ushort, __float2bfloat16(v0));
        pk.y = __builtin_bit_cast(ushort, __float2bfloat16(v1));
        pk.z = __builtin_bit_cast(ushort, __float2bfloat16(v2));
        pk.w = __builtin_bit_cast(ushort, __float2bfloat16(v3));
        *(ushort4*)((bf16*)Cp + ci) = pk;
      }
    } else {
#pragma unroll
      for (int m = 0; m < 4; ++m) {
#pragma unroll
        for (int rr = 0; rr < 4; ++rr) {
          const int grow = m0 + wm + m * 16 + rg + rr;
          float v = acc[m][n][rr] + bias;
          if (RELU) v = fmaxf(v, 0.f);
          const long ci = (long)z * sCz + (long)(grow >> 10) * sCb
                        + (long)(grow & 1023) * sCs + (long)gcol * sCn;
          if (OUT_BF16) ((bf16*)Cp)[ci] = __float2bfloat16(v);
          else          ((float*)Cp)[ci] = v;
        }
      }
    }
  }
}

// ---------------- fp32 [Kd,Nd] -> bf16 [Nd,Kd] transpose ----------------
__global__ __launch_bounds__(256) void transpose_kernel(
    const float* __restrict__ in, long sInZ, int ldin,
    bf16* __restrict__ out, long sOutZ, int ldout)
{
  __shared__ float t[64][65];
  const int tid = threadIdx.x;
  const int n0 = blockIdx.x * 64, k0 = blockIdx.y * 64;
  const float* ip = in + (long)blockIdx.z * sInZ;
  bf16* op = out + (long)blockIdx.z * sOutZ;
  const int cx = (tid & 15) * 4, ry = tid >> 4;
#pragma unroll
  for (int p = 0; p < 4; ++p) {
    const int k = ry + p * 16;
    const float4 v = *(const float4*)(ip + (long)(k0 + k) * ldin + n0 + cx);
    t[k][cx] = v.x; t[k][cx + 1] = v.y; t[k][cx + 2] = v.z; t[k][cx + 3] = v.w;
  }
  __syncthreads();
#pragma unroll
  for (int p = 0; p < 4; ++p) {
    const int n = ry + p * 16;
    ushort4 o;
    o.x = __builtin_bit_cast(ushort, __float2bfloat16(t[cx + 0][n]));
    o.y = __builtin_bit_cast(ushort, __float2bfloat16(t[cx + 1][n]));
    o.z = __builtin_bit_cast(ushort, __float2bfloat16(t[cx + 2][n]));
    o.w = __builtin_bit_cast(ushort, __float2bfloat16(t[cx + 3][n]));
    *(ushort4*)(op + (long)(n0 + n) * ldout + k0 + cx) = o;
  }
}

// ---------------- stacked Q/K bias ----------------
__global__ void biasqk_kernel(const float* __restrict__ bq, const float* __restrict__ bk,
                              float* __restrict__ out) {
  const int i = blockIdx.x * 256 + threadIdx.x;
  if (i < NH * 128) {
    const int h = i >> 7, n = i & 127;
    out[i] = (n < 64) ? bq[h * 64 + n] : bk[h * 64 + n - 64];
  }
}

// ---------------- xmean pipeline (analytic pad-row attention) ----------------
__global__ __launch_bounds__(256) void xpart_kernel(
    const float* __restrict__ x, float* __restrict__ xpart) {
  const int b = blockIdx.x, g = blockIdx.y;
  const int tid = threadIdx.x;
  const float* xp = x + (long)b * SQ * DM + (long)g * 64 * DM;
  float a0 = 0.f, a1 = 0.f, a2 = 0.f;
  for (int s = 0; s < 64; ++s) {
    a0 += xp[(long)s * DM + tid];
    a1 += xp[(long)s * DM + tid + 256];
    a2 += xp[(long)s * DM + tid + 512];
  }
  float* op = xpart + (long)(b * 16 + g) * DM;
  op[tid] = a0; op[tid + 256] = a1; op[tid + 512] = a2;
}

__global__ void xmeanf_kernel(const float* __restrict__ xpart, float* __restrict__ xmean) {
  const int b = blockIdx.x;
  const int d = threadIdx.x;   // 768 threads
  float a = 0.f;
#pragma unroll
  for (int g = 0; g < 16; ++g) a += xpart[(long)(b * 16 + g) * DM + d];
  xmean[b * DM + d] = a * (1.0f / (float)SQ);
}

__global__ __launch_bounds__(256) void vmeanw_kernel(
    const float* __restrict__ xmean, const bf16* __restrict__ wvT,
    const float* __restrict__ bv, float* __restrict__ vmean) {
  const int tid = threadIdx.x;
  const int w = blockIdx.x * 4 + (tid >> 6);   // 0..1535
  const int b = w / DM;
  const int e = w % DM;
  const int lane = tid & 63;
  float xm[12];
#pragma unroll
  for (int j = 0; j < 12; ++j) xm[j] = xmean[b * DM + lane + j * 64];
  float acc = 0.f;
  for (int h = 0; h < NH; ++h) {
    const bf16* wr = wvT + ((long)h * DM + e) * DM;
#pragma unroll
    for (int j = 0; j < 12; ++j)
      acc += xm[j] * __bfloat162float(wr[lane + j * 64]);
  }
#pragma unroll
  for (int o = 32; o >= 1; o >>= 1) acc += __shfl_xor(acc, o);
  if (lane == 0) {
    float bs = 0.f;
#pragma unroll
    for (int h = 0; h < NH; ++h) bs += bv[h * DM + e];
    vmean[b * DM + e] = (acc + bs) * (1.0f / (float)NH);
  }
}

// ---------------- embedding + PE -> x fp32 + xb bf16 ----------------
__global__ __launch_bounds__(256) void embed_kernel(
    const int* __restrict__ tok, const float* __restrict__ emb,
    float* __restrict__ x, bf16* __restrict__ xb)
{
  const int gid = blockIdx.x * 256 + threadIdx.x;
  const int row = gid / (DM / 4);
  const int dc  = (gid % (DM / 4)) * 4;
  const int t = tok[row];
  const int s = row & (SQ - 1);
#pragma unroll
  for (int j = 0; j < 4; ++j) {
    const int d = dc + j;
    const float e = emb[(long)t * DM + d];
    const float div = expf(-(float)(d & ~1) * (9.210340371976184f / (float)DM));
    const float ang = (float)s * div;
    const float pe = (d & 1) ? cosf(ang) : sinf(ang);
    const float v = e + pe;
    x[(long)row * DM + d] = v;
    xb[(long)row * DM + d] = __float2bfloat16(v);
  }
}

// ---------------- masked softmax ----------------
__global__ __launch_bounds__(256) void softmax_kernel(
    bf16* __restrict__ P, const int* __restrict__ tok)
{
  const int row = blockIdx.x;
  const int s = row & (SQ - 1);
  const int z = row >> 10;
  const int b = z / NH;
  bf16* sp = P + (long)row * SQ;
  const int* tb = tok + b * SQ;
  const int tid = threadIdx.x;
  const int t0 = tid * 4;

  if (tb[s] == 0) {
    const bf16 u = __float2bfloat16(1.0f / (float)SQ);
    sp[t0] = u; sp[t0 + 1] = u; sp[t0 + 2] = u; sp[t0 + 3] = u;
    return;
  }
  uint2 raw = *(const uint2*)(sp + t0);
  int4 tv = *(const int4*)(tb + t0);
  const bf16* rh = (const bf16*)&raw;
  const int tvv[4] = {tv.x, tv.y, tv.z, tv.w};
  float val[4];
  float vmax = -1e30f;
#pragma unroll
  for (int j = 0; j < 4; ++j) {
    const int t = t0 + j;
    const bool valid = (t <= s) && (tvv[j] != 0);
    val[j] = valid ? __bfloat162float(rh[j]) * 0.125f : -1e30f;
    vmax = fmaxf(vmax, val[j]);
  }
  __shared__ float red[4];
  const int lane = tid & 63, wid = tid >> 6;
  float w = vmax;
#pragma unroll
  for (int o = 32; o >= 1; o >>= 1) w = fmaxf(w, __shfl_xor(w, o));
  if (lane == 0) red[wid] = w;
  __syncthreads();
  const float Mx = fmaxf(fmaxf(red[0], red[1]), fmaxf(red[2], red[3]));
  __syncthreads();
  float e[4]; float lsum = 0.f;
#pragma unroll
  for (int j = 0; j < 4; ++j) {
    e[j] = (val[j] > -1e29f) ? expf(val[j] - Mx) : 0.f;
    lsum += e[j];
  }
  w = lsum;
#pragma unroll
  for (int o = 32; o >= 1; o >>= 1) w += __shfl_xor(w, o);
  if (lane == 0) red[wid] = w;
  __syncthreads();
  const float inv = 1.0f / (red[0] + red[1] + red[2] + red[3]);
#pragma unroll
  for (int j = 0; j < 4; ++j) sp[t0 + j] = __float2bfloat16(e[j] * inv);
}

// ---------------- residual (+head-mean / pad-override) + LayerNorm ----------------
template<int MODE>
__global__ __launch_bounds__(256) void ln_kernel(
    float* __restrict__ x, bf16* __restrict__ xb,
    const float* __restrict__ tmp, const bf16* __restrict__ heads,
    const float* __restrict__ g, const float* __restrict__ be,
    const int* __restrict__ tok, const float* __restrict__ vmean)
{
  const int r = blockIdx.x;
  const int b = r >> 10;
  const int tid = threadIdx.x;
  const bool pad = (MODE == 1) && (tok[r] == 0);
  float vals[3];
  float sum = 0.f, sq = 0.f;
#pragma unroll
  for (int i = 0; i < 3; ++i) {
    const int d = tid + i * 256;
    const float a = x[(long)r * DM + d];
    float t;
    if (MODE == 0) {
      t = tmp[(long)r * DM + d];
    } else if (pad) {
      t = vmean[b * DM + d];
    } else {
      const int s = r & (SQ - 1);
      float hs = 0.f;
#pragma unroll
      for (int h = 0; h < NH; ++h)
        hs += __bfloat162float(heads[((long)(b * NH + h) * SQ + s) * DM + d]);
      t = hs * (1.0f / (float)NH);
    }
    const float vv = a + t;
    vals[i] = vv;
    sum += vv; sq += vv * vv;
  }
  __shared__ float rs[4], rq[4];
  const int lane = tid & 63, wid = tid >> 6;
  float s1 = sum, s2 = sq;
#pragma unroll
  for (int o = 32; o >= 1; o >>= 1) { s1 += __shfl_xor(s1, o); s2 += __shfl_xor(s2, o); }
  if (lane == 0) { rs[wid] = s1; rq[wid] = s2; }
  __syncthreads();
  const float S1 = rs[0] + rs[1] + rs[2] + rs[3];
  const float S2 = rq[0] + rq[1] + rq[2] + rq[3];
  const float mean = S1 * (1.0f / (float)DM);
  const float var  = S2 * (1.0f / (float)DM) - mean * mean;
  const float rstd = rsqrtf(var + 1e-5f);
#pragma unroll
  for (int i = 0; i < 3; ++i) {
    const int d = tid + i * 256;
    const float o = (vals[i] - mean) * rstd * g[d] + be[d];
    x[(long)r * DM + d] = o;
    xb[(long)r * DM + d] = __float2bfloat16(o);
  }
}

extern "C" void kernel_launch(void* const* d_in, const int* in_sizes, int n_in,
                              void* d_out, int out_size, void* d_ws, size_t ws_size,
                              hipStream_t stream) {
  const int expect_sizes[18] = {
    2048, 24576000, 3538944, 4608, 3538944, 4608, 42467328, 55296,
    4608, 4608, 4608, 4608, 14155776, 18432, 14155776, 4608, 24576000, 32000
  };
  bool sizes_ok = (n_in == 18);
  if (sizes_ok)
    for (int i = 0; i < 18; ++i) sizes_ok = sizes_ok && (in_sizes[i] == expect_sizes[i]);
  if (!sizes_ok) {
    fill_kernel<<<2048, 256, 0, stream>>>((float*)d_out, (long)out_size, 1000.0f);
    return;
  }
  if (out_size != 65536000) {
    fill_kernel<<<2048, 256, 0, stream>>>((float*)d_out, (long)out_size, 3000.0f);
    return;
  }
  if (ws_size < 158189568ull) {
    fill_kernel<<<2048, 256, 0, stream>>>((float*)d_out, (long)out_size, 2000.0f);
    return;
  }

  const int*   tok  = (const int*)d_in[0];
  const float* emb  = (const float*)d_in[1];
  const float* Wq   = (const float*)d_in[2];
  const float* bq   = (const float*)d_in[3];
  const float* Wk   = (const float*)d_in[4];
  const float* bk   = (const float*)d_in[5];
  const float* Wv   = (const float*)d_in[6];
  const float* bv   = (const float*)d_in[7];
  const float* g1   = (const float*)d_in[8];
  const float* be1  = (const float*)d_in[9];
  const float* g2   = (const float*)d_in[10];
  const float* be2  = (const float*)d_in[11];
  const float* W1   = (const float*)d_in[12];
  const float* b1   = (const float*)d_in[13];
  const float* W2   = (const float*)d_in[14];
  const float* b2   = (const float*)d_in[15];
  const float* Wout = (const float*)d_in[16];
  const float* bout = (const float*)d_in[17];

  char* ws = (char*)d_ws;
  float* x      = (float*)(ws + 0);
  bf16*  xb     = (bf16*) (ws + 6291456);
  bf16*  qk     = (bf16*) (ws + 9437184);
  float* tmp    = (float*)(ws + 9437184);
  bf16*  vT     = (bf16*) (ws + 15728640);
  bf16*  P      = (bf16*) (ws + 53477376);
  bf16*  ff     = (bf16*) (ws + 53477376);
  bf16*  woutT  = (bf16*) (ws + 53477376);
  bf16*  heads  = (bf16*) (ws + 103809024);
  bf16*  wqkT   = (bf16*) (ws + 141557760);
  bf16*  wvT    = (bf16*) (ws + 143917056);
  bf16*  w1T    = (bf16*) (ws + 141557760);
  bf16*  w2T    = (bf16*) (ws + 146276352);
  float* biasqk = (float*)(ws + 158072832);
  float* xpart  = (float*)(ws + 158078976);
  float* xmean  = (float*)(ws + 158177280);
  float* vmean  = (float*)(ws + 158183424);

  embed_kernel<<<dim3((2 * SQ * DM / 4) / 256), 256, 0, stream>>>(tok, emb, x, xb);

  for (int l = 0; l < NL; ++l) {
    transpose_kernel<<<dim3(1, 12, NH), 256, 0, stream>>>(
        Wq + (long)l * NH * DM * KDH, (long)DM * KDH, KDH,
        wqkT, 128 * DM, DM);
    transpose_kernel<<<dim3(1, 12, NH), 256, 0, stream>>>(
        Wk + (long)l * NH * DM * KDH, (long)DM * KDH, KDH,
        wqkT + 64 * DM, 128 * DM, DM);
    transpose_kernel<<<dim3(12, 12, NH), 256, 0, stream>>>(
        Wv + (long)l * NH * DM * DM, (long)DM * DM, DM,
        wvT, (long)DM * DM, DM);
    biasqk_kernel<<<6, 256, 0, stream>>>(bq + l * NH * KDH, bk + l * NH * KDH, biasqk);

    // analytic pad-row attention input
    xpart_kernel<<<dim3(2, 16), 256, 0, stream>>>(x, xpart);
    xmeanf_kernel<<<dim3(2), 768, 0, stream>>>(xpart, xmean);
    vmeanw_kernel<<<dim3(384), 256, 0, stream>>>(xmean, wvT, bv + (long)l * NH * DM, vmean);

    // fused Q|K projection
    gemm_bt<true, false><<<dim3(16, 1, NH), 256, 0, stream>>>(
        2048, 128, DM, xb, 0, DM, wqkT, (long)128 * DM, DM,
        biasqk, 128,
        qk, (long)SQ * 128, (long)NH * SQ * 128, 128, 1);
    // V projection, written transposed vT[b,h,e,s]
    gemm_bt<true, false><<<dim3(16, 6, NH), 256, 0, stream>>>(
        2048, DM, DM, xb, 0, DM, wvT, (long)DM * DM, DM,
        bv + (long)l * NH * DM, DM,
        vT, (long)DM * SQ, (long)NH * DM * SQ, 1, SQ);
    // scores = Q @ K^T -> P (causal tile skip)
    gemm_bt<true, false, true, false><<<dim3(8, 8, 2 * NH), 256, 0, stream>>>(
        SQ, SQ, KDH, qk, (long)SQ * 128, 128, qk + 64, (long)SQ * 128, 128,
        (const float*)nullptr, 0,
        P, (long)SQ * SQ, 0, SQ, 1);
    softmax_kernel<<<dim3(2 * NH * SQ), 256, 0, stream>>>(P, tok);
    // heads = P @ V (causal K-truncation)
    gemm_bt<true, false, false, true><<<dim3(8, 6, 2 * NH), 256, 0, stream>>>(
        SQ, DM, SQ, P, (long)SQ * SQ, SQ, vT, (long)DM * SQ, SQ,
        (const float*)nullptr, 0,
        heads, (long)SQ * DM, 0, DM, 1);
    ln_kernel<1><<<dim3(2048), 256, 0, stream>>>(x, xb, nullptr, heads,
                                                 g1 + l * DM, be1 + l * DM, tok, vmean);
    transpose_kernel<<<dim3(48, 12, 1), 256, 0, stream>>>(
        W1 + (long)l * DM * FFD, 0, FFD, w1T, 0, DM);
    transpose_kernel<<<dim3(12, 48, 1), 256, 0, stream>>>(
        W2 + (long)l * FFD * DM, 0, DM, w2T, 0, FFD);
    gemm_bt<true, true><<<dim3(16, 24, 1), 256, 0, stream>>>(
        2048, FFD, DM, xb, 0, DM, w1T, 0, DM,
        b1 + (long)l * FFD, 0,
        ff, 0, (long)SQ * FFD, FFD, 1);
    gemm_bt<false, false><<<dim3(16, 6, 1), 256, 0, stream>>>(
        2048, DM, FFD, ff, 0, FFD, w2T, 0, FFD,
        b2 + (long)l * DM, 0,
        tmp, 0, (long)SQ * DM, DM, 1);
    ln_kernel<0><<<dim3(2048), 256, 0, stream>>>(x, xb, tmp, nullptr,
                                                 g2 + l * DM, be2 + l * DM, tok, nullptr);
  }
  transpose_kernel<<<dim3(500, 12, 1), 256, 0, stream>>>(Wout, 0, NV, woutT, 0, DM);
  gemm_bt<false, false><<<dim3(16, 250, 1), 256, 0, stream>>>(
      2048, NV, DM, xb, 0, DM, woutT, 0, DM,
      bout, 0,
      d_out, 0, (long)SQ * NV, NV, 1);
}